// Round 3
// baseline (9896.204 us; speedup 1.0000x reference)
//
#include <hip/hip_runtime.h>
#include <hip/hip_bf16.h>

#define DI __device__ __forceinline__

constexpr int S_ = 2048;
constexpr int D_ = 1024;
constexpr int H_ = 16;
constexpr int HD_ = 64;
constexpr int BH_ = 32;      // B*H
constexpr int NKEEP = 675;   // max(int(2048*0.33), 2)

DI float wsum(float v) {
#pragma unroll
  for (int o = 32; o > 0; o >>= 1) v += __shfl_xor(v, o, 64);
  return v;
}
DI float wmaxr(float v) {
#pragma unroll
  for (int o = 32; o > 0; o >>= 1) v = fmaxf(v, __shfl_xor(v, o, 64));
  return v;
}
DI float wminr(float v) {
#pragma unroll
  for (int o = 32; o > 0; o >>= 1) v = fminf(v, __shfl_xor(v, o, 64));
  return v;
}

// ---------------------------------------------------------------------------
// K1: qkv = x @ qkv_w^T + qkv_b, scattered to q/k/v (B,H,S,64) f32
// k-major LDS tiles -> inner loop is 2x ds_read_b128 + 16 FMA per kk.
// ---------------------------------------------------------------------------
__global__ __launch_bounds__(256) void k_gemm_qkv(
    const float* __restrict__ x, const float* __restrict__ w,
    const float* __restrict__ bias, float* __restrict__ q,
    float* __restrict__ kbuf, float* __restrict__ vbuf) {
  __shared__ float As[32][68];   // As[k][m]
  __shared__ float Bs[32][68];   // Bs[k][n]
  const int tid = threadIdx.x;
  const int m0 = blockIdx.y * 64;
  const int n0 = blockIdx.x * 64;
  const int tx = tid & 15, ty = tid >> 4;
  const int srow = tid & 63, sk = (tid >> 6) * 8;
  float c[4][4] = {};
  for (int k0 = 0; k0 < D_; k0 += 32) {
    const float* xp = x + (size_t)(m0 + srow) * D_ + k0 + sk;
    const float* wp = w + (size_t)(n0 + srow) * D_ + k0 + sk;
    float4 fa0 = *reinterpret_cast<const float4*>(xp);
    float4 fa1 = *reinterpret_cast<const float4*>(xp + 4);
    float4 fb0 = *reinterpret_cast<const float4*>(wp);
    float4 fb1 = *reinterpret_cast<const float4*>(wp + 4);
    __syncthreads();
    As[sk + 0][srow] = fa0.x; As[sk + 1][srow] = fa0.y;
    As[sk + 2][srow] = fa0.z; As[sk + 3][srow] = fa0.w;
    As[sk + 4][srow] = fa1.x; As[sk + 5][srow] = fa1.y;
    As[sk + 6][srow] = fa1.z; As[sk + 7][srow] = fa1.w;
    Bs[sk + 0][srow] = fb0.x; Bs[sk + 1][srow] = fb0.y;
    Bs[sk + 2][srow] = fb0.z; Bs[sk + 3][srow] = fb0.w;
    Bs[sk + 4][srow] = fb1.x; Bs[sk + 5][srow] = fb1.y;
    Bs[sk + 6][srow] = fb1.z; Bs[sk + 7][srow] = fb1.w;
    __syncthreads();
#pragma unroll 8
    for (int kk = 0; kk < 32; ++kk) {
      const float4 a4 = *reinterpret_cast<const float4*>(&As[kk][ty * 4]);
      const float4 b4 = *reinterpret_cast<const float4*>(&Bs[kk][tx * 4]);
      const float a[4] = {a4.x, a4.y, a4.z, a4.w};
      const float b[4] = {b4.x, b4.y, b4.z, b4.w};
#pragma unroll
      for (int i = 0; i < 4; ++i)
#pragma unroll
        for (int j = 0; j < 4; ++j) c[i][j] = fmaf(a[i], b[j], c[i][j]);
    }
  }
#pragma unroll
  for (int j = 0; j < 4; ++j) {
    const int n = n0 + tx * 4 + j;
    const float bb = bias[n];
    const int which = n >> 10, rem = n & 1023;
    const int hh = rem >> 6, dd = rem & 63;
    float* dst = (which == 0) ? q : (which == 1) ? kbuf : vbuf;
#pragma unroll
    for (int i = 0; i < 4; ++i) {
      const int m = m0 + ty * 4 + i;
      const int bb2 = m >> 11, ss = m & (S_ - 1);
      dst[(((size_t)(bb2 * H_ + hh)) * S_ + ss) * HD_ + dd] = c[i][j] + bb;
    }
  }
}

// ---------------------------------------------------------------------------
// K2: per (b,h): centroid, d2c[s], sq[s], d2cmax
// ---------------------------------------------------------------------------
__global__ __launch_bounds__(256) void k_centroid(
    const float* __restrict__ x, float* __restrict__ d2c,
    float* __restrict__ sqn, float* __restrict__ d2cmax) {
  const int bh = blockIdx.x, b = bh >> 4, h = bh & 15;
  const int tid = threadIdx.x;
  const int d = tid & 63, w = tid >> 6;
  __shared__ float cpart[4][64];
  __shared__ float cent[64];
  __shared__ float wmax[4];
  const float* xb = x + (size_t)b * S_ * D_ + h * HD_;
  float part = 0.f;
  for (int s = w; s < S_; s += 4) part += xb[(size_t)s * D_ + d];
  cpart[w][d] = part;
  __syncthreads();
  if (tid < 64)
    cent[tid] = (cpart[0][tid] + cpart[1][tid] + cpart[2][tid] + cpart[3][tid]) * (1.f / 2048.f);
  __syncthreads();
  const float cd = cent[d];
  float lmax = 0.f;
  for (int s = w; s < S_; s += 4) {
    float val = xb[(size_t)s * D_ + d];
    float df = val - cd;
    float s1 = wsum(df * df);
    float s2 = wsum(val * val);
    if (d == 0) {
      float r = sqrtf(s1);
      d2c[bh * S_ + s] = r;
      sqn[bh * S_ + s] = s2;
      lmax = fmaxf(lmax, r);
    }
  }
  if (d == 0) wmax[w] = lmax;
  __syncthreads();
  if (tid == 0) d2cmax[bh] = fmaxf(fmaxf(wmax[0], wmax[1]), fmaxf(wmax[2], wmax[3]));
}

// branch-free sorted insert (ascending top[0..9])
DI void insert10(float* top, float v) {
#pragma unroll
  for (int j = 9; j >= 1; --j) top[j] = fmaxf(fminf(v, top[j]), top[j - 1]);
  top[0] = fminf(v, top[0]);
}

// ---------------------------------------------------------------------------
// K3: per row s: mmd[s] = sqrt(10th-smallest of clamp(sq_s+sq_t-2*dot,0))
// 32 rows per block (8 per wave), b128 LDS reads. grid (64, 32).
// Candidate->lane mapping identical to v1 (lane sees keys t0+lane, t0+64+lane)
// and ascending-dd FMA order -> bit-identical distances.
// ---------------------------------------------------------------------------
__global__ __launch_bounds__(256) void k_kth(
    const float* __restrict__ x, const float* __restrict__ sqn,
    float* __restrict__ mmd) {
  const int bh = blockIdx.y, b = bh >> 4, h = bh & 15;
  const int s0 = blockIdx.x * 32;
  const int tid = threadIdx.x;
  const int w = tid >> 6, lane = tid & 63;
  __shared__ float Xt[128][68];
  __shared__ float sRow[32][68];
  __shared__ float sq32[32];
  const float* xb = x + (size_t)b * S_ * D_ + h * HD_;
  // stage the 32 q-rows: 32x64 floats, 8 per thread
  {
    const int r = tid >> 3, c4 = (tid & 7) * 8;
    const float* sp = xb + (size_t)(s0 + r) * D_ + c4;
    float4 f0 = *reinterpret_cast<const float4*>(sp);
    float4 f1 = *reinterpret_cast<const float4*>(sp + 4);
    *reinterpret_cast<float4*>(&sRow[r][c4]) = f0;
    *reinterpret_cast<float4*>(&sRow[r][c4 + 4]) = f1;
  }
  if (tid < 32) sq32[tid] = sqn[bh * S_ + s0 + tid];
  float top[8][10];
#pragma unroll
  for (int r = 0; r < 8; ++r)
#pragma unroll
    for (int i = 0; i < 10; ++i) top[r][i] = __builtin_inff();
  const int r0 = w * 8;
  for (int t0 = 0; t0 < S_; t0 += 128) {
    __syncthreads();
#pragma unroll
    for (int it = 0; it < 8; ++it) {
      const int g = it * 256 + tid;
      const int rr = g >> 4, d0 = (g & 15) * 4;
      float4 f = *reinterpret_cast<const float4*>(xb + (size_t)(t0 + rr) * D_ + d0);
      *reinterpret_cast<float4*>(&Xt[rr][d0]) = f;
    }
    __syncthreads();
    float acc[8][2] = {};
#pragma unroll
    for (int d4 = 0; d4 < 64; d4 += 4) {
      const float4 ka = *reinterpret_cast<const float4*>(&Xt[lane][d4]);
      const float4 kb2 = *reinterpret_cast<const float4*>(&Xt[lane + 64][d4]);
#pragma unroll
      for (int r = 0; r < 8; ++r) {
        const float4 qv = *reinterpret_cast<const float4*>(&sRow[r0 + r][d4]);
        // ascending-dd chain: (((acc+qx*kx)+qy*ky)+qz*kz)+qw*kw
        acc[r][0] = fmaf(qv.w, ka.w, fmaf(qv.z, ka.z, fmaf(qv.y, ka.y, fmaf(qv.x, ka.x, acc[r][0]))));
        acc[r][1] = fmaf(qv.w, kb2.w, fmaf(qv.z, kb2.z, fmaf(qv.y, kb2.y, fmaf(qv.x, kb2.x, acc[r][1]))));
      }
    }
    const float sqa = sqn[bh * S_ + t0 + lane];
    const float sqb = sqn[bh * S_ + t0 + 64 + lane];
#pragma unroll
    for (int r = 0; r < 8; ++r) {
      const float sq_s = sq32[r0 + r];
      const float v0 = fmaxf(sq_s + sqa - 2.f * acc[r][0], 0.f);
      const float v1 = fmaxf(sq_s + sqb - 2.f * acc[r][1], 0.f);
      if (v0 < top[r][9]) insert10(top[r], v0);
      if (v1 < top[r][9]) insert10(top[r], v1);
    }
  }
  // wave-level multiset merge per row: extract global 10 smallest
#pragma unroll
  for (int r = 0; r < 8; ++r) {
    float kth = 0.f;
    for (int it = 0; it < 10; ++it) {
      const float mn = wminr(top[r][0]);
      unsigned long long ball = __ballot(top[r][0] == mn);
      const int src = __ffsll(ball) - 1;
      if (lane == src) {
#pragma unroll
        for (int j = 0; j < 9; ++j) top[r][j] = top[r][j + 1];
        top[r][9] = __builtin_inff();
      }
      kth = mn;
    }
    if (lane == 0) mmd[bh * S_ + s0 + r0 + r] = sqrtf(kth);
  }
}

// ---------------------------------------------------------------------------
// K4: per (b,h) max over mmd
// ---------------------------------------------------------------------------
__global__ __launch_bounds__(256) void k_maxreduce(
    const float* __restrict__ src, float* __restrict__ dst) {
  const int bh = blockIdx.x, tid = threadIdx.x;
  float m = 0.f;
  for (int s = tid; s < S_; s += 256) m = fmaxf(m, src[bh * S_ + s]);
  __shared__ float red[256];
  red[tid] = m;
  __syncthreads();
  for (int o = 128; o > 0; o >>= 1) {
    if (tid < o) red[tid] = fmaxf(red[tid], red[tid + o]);
    __syncthreads();
  }
  if (tid == 0) dst[bh] = red[0];
}

// ---------------------------------------------------------------------------
// K5: tls = 0.7*d2c/(d2cmax+1e-8) + 0.3*mmd/(mmdmax+1e-8); top-675 -> mask
// index-stable tie-break matching jax.lax.top_k
// ---------------------------------------------------------------------------
__global__ __launch_bounds__(256) void k_topk(
    const float* __restrict__ d2c, const float* __restrict__ mmd,
    const float* __restrict__ d2cmax, const float* __restrict__ mmdmax,
    unsigned char* __restrict__ lmask) {
  const int bh = blockIdx.x, tid = threadIdx.x;
  __shared__ float vals[S_];
  __shared__ int red[256];
  const float dden = d2cmax[bh] + 1e-8f;
  const float mden = mmdmax[bh] + 1e-8f;
  for (int s = tid; s < S_; s += 256) {
    float lift = d2c[bh * S_ + s] / dden;
    float mn = mmd[bh * S_ + s] / mden;
    vals[s] = 0.7f * lift + 0.3f * mn;
  }
  __syncthreads();
  // binary search on float bits (all vals >= 0) for the 675th largest value
  unsigned lo = 0u, hi = 0x7f800000u;
  while (hi - lo > 1u) {
    unsigned mid = (lo + hi) >> 1;
    float T = __uint_as_float(mid);
    int cc = 0;
    for (int s = tid; s < S_; s += 256) cc += (vals[s] >= T);
    red[tid] = cc;
    __syncthreads();
    for (int o = 128; o > 0; o >>= 1) {
      if (tid < o) red[tid] += red[tid + o];
      __syncthreads();
    }
    int cnt = red[0];
    __syncthreads();
    if (cnt >= NKEEP) lo = mid; else hi = mid;
  }
  const float v675 = __uint_as_float(lo);
  int cc = 0;
  for (int s = tid; s < S_; s += 256) cc += (vals[s] > v675);
  red[tid] = cc;
  __syncthreads();
  for (int o = 128; o > 0; o >>= 1) {
    if (tid < o) red[tid] += red[tid + o];
    __syncthreads();
  }
  const int need = NKEEP - red[0];
  __syncthreads();
  for (int s = tid; s < S_; s += 256) {
    float vv = vals[s];
    int sel = vv > v675;
    if (!sel && vv == v675) {
      int r = 0;
      for (int t = 0; t < s; ++t) r += (vals[t] == v675);
      sel = (r < need);
    }
    lmask[bh * S_ + s] = (unsigned char)sel;
  }
}

// ---------------------------------------------------------------------------
// K6: scores + mask + softmax -> attn.  Flash-style two-pass.
// ---------------------------------------------------------------------------
__global__ __launch_bounds__(256, 3) void k_attn(
    const float* __restrict__ q, const float* __restrict__ k,
    const unsigned char* __restrict__ lmask, float* __restrict__ attn) {
  const int bid = blockIdx.x;
  const int wg = (bid & 7) * 128 + (bid >> 3);   // bijective XCD swizzle (1024 = 8*128)
  const int bh = wg >> 5;
  const int s0 = (wg & 31) * 64;
  const int tid = threadIdx.x;
  const int tx = tid & 31, ty = tid >> 5;

  __shared__ float Qt[64][68];          // transposed: Qt[dd][row]
  __shared__ float Ks[128][65];         // Ks[col][dd]
  __shared__ unsigned char lm[S_];

  const float* qb = q + (size_t)bh * S_ * HD_;
  const float* kb = k + (size_t)bh * S_ * HD_;

  {
    const unsigned* lm32 = reinterpret_cast<const unsigned*>(lmask + bh * S_);
    unsigned* dl = reinterpret_cast<unsigned*>(lm);
    dl[tid] = lm32[tid];
    dl[tid + 256] = lm32[tid + 256];
#pragma unroll
    for (int it = 0; it < 4; ++it) {
      const int g = it * 256 + tid;
      const int r = g >> 4, d0 = (g & 15) * 4;
      float4 f = *reinterpret_cast<const float4*>(qb + (size_t)(s0 + r) * HD_ + d0);
      Qt[d0 + 0][r] = f.x; Qt[d0 + 1][r] = f.y;
      Qt[d0 + 2][r] = f.z; Qt[d0 + 3][r] = f.w;
    }
  }

  constexpr float SCL = 0.18033688011112042f;   // 0.125 * log2(e)
  constexpr float MB2 = -14426.950408889634f;   // -10000 * log2(e)

  const int row0 = ty * 8;
  const int col0 = tx * 4;
  const int rg0 = s0 + row0;

  float m[8], l[8], invl[8];
#pragma unroll
  for (int i = 0; i < 8; ++i) { m[i] = MB2; l[i] = 0.f; invl[i] = 0.f; }

  for (int pass = 0; pass < 2; ++pass) {
    for (int t = 0; t < 16; ++t) {
      const int t0 = t * 128;
      __syncthreads();
#pragma unroll
      for (int it = 0; it < 8; ++it) {
        const int g = it * 256 + tid;
        const int r = g >> 4, d0 = (g & 15) * 4;
        float4 f = *reinterpret_cast<const float4*>(kb + (size_t)(t0 + r) * HD_ + d0);
        Ks[r][d0 + 0] = f.x; Ks[r][d0 + 1] = f.y;
        Ks[r][d0 + 2] = f.z; Ks[r][d0 + 3] = f.w;
      }
      __syncthreads();

      float acc[8][4] = {};
      const float* ksp = &Ks[col0][0];
#pragma unroll 4
      for (int dd = 0; dd < 64; ++dd) {
        const float4 a0 = *reinterpret_cast<const float4*>(&Qt[dd][row0]);
        const float4 a1 = *reinterpret_cast<const float4*>(&Qt[dd][row0 + 4]);
        const float a[8] = {a0.x, a0.y, a0.z, a0.w, a1.x, a1.y, a1.z, a1.w};
        const float b[4] = {ksp[0 * 65 + dd], ksp[1 * 65 + dd],
                            ksp[2 * 65 + dd], ksp[3 * 65 + dd]};
#pragma unroll
        for (int i = 0; i < 8; ++i)
#pragma unroll
          for (int j = 0; j < 4; ++j) acc[i][j] = fmaf(a[i], b[j], acc[i][j]);
      }

      const int cg0 = t0 + col0;
      bool kc[4];
#pragma unroll
      for (int j = 0; j < 4; ++j) kc[j] = lm[cg0 + j] != 0;

      if (pass == 0) {
#pragma unroll
        for (int i = 0; i < 8; ++i) {
          const int rel0 = cg0 - (rg0 + i) + 64;   // keep iff 0 <= rel0+j <= 128
          float s[4];
#pragma unroll
          for (int j = 0; j < 4; ++j) {
            const bool kp = kc[j] || ((unsigned)(rel0 + j) <= 128u);
            s[j] = kp ? acc[i][j] * SCL : MB2;
          }
          const float tm = fmaxf(fmaxf(s[0], s[1]), fmaxf(s[2], s[3]));
          const float nm = fmaxf(m[i], tm);
          const float add = exp2f(s[0] - nm) + exp2f(s[1] - nm) +
                            exp2f(s[2] - nm) + exp2f(s[3] - nm);
          l[i] = l[i] * exp2f(m[i] - nm) + add;
          m[i] = nm;
        }
      } else {
        float* ap = attn + ((size_t)bh * S_ + rg0) * S_ + cg0;
#pragma unroll
        for (int i = 0; i < 8; ++i) {
          const int rel0 = cg0 - (rg0 + i) + 64;
          float o[4];
#pragma unroll
          for (int j = 0; j < 4; ++j) {
            const bool kp = kc[j] || ((unsigned)(rel0 + j) <= 128u);
            o[j] = kp ? exp2f(acc[i][j] * SCL - m[i]) * invl[i] : 0.f;
          }
          *reinterpret_cast<float4*>(ap + (size_t)i * S_) =
              make_float4(o[0], o[1], o[2], o[3]);
        }
      }
    }
    if (pass == 0) {
#pragma unroll
      for (int i = 0; i < 8; ++i) {
        float mi = m[i], li = l[i];
#pragma unroll
        for (int off = 1; off <= 16; off <<= 1) {
          const float om = __shfl_xor(mi, off, 64);
          const float ol = __shfl_xor(li, off, 64);
          const float nm = fmaxf(mi, om);
          li = li * exp2f(mi - nm) + ol * exp2f(om - nm);
          mi = nm;
        }
        m[i] = mi; l[i] = li; invl[i] = 1.f / li;
      }
    }
  }
}

// ---------------------------------------------------------------------------
// K7: ao(b,s,h*64+d) = attn(bh,s,:) @ v(bh,:,d)   k-major LDS, b128 reads
// ---------------------------------------------------------------------------
__global__ __launch_bounds__(256) void k_av(
    const float* __restrict__ attn, const float* __restrict__ v,
    float* __restrict__ ao) {
  const int bh = blockIdx.y, b = bh >> 4, h = bh & 15;
  const int s0 = blockIdx.x * 64;
  const int tid = threadIdx.x, tx = tid & 15, ty = tid >> 4;
  __shared__ float As[32][68];   // As[k][s]
  __shared__ float Bs[32][68];   // Bs[k][d]
  const float* ab = attn + (size_t)bh * S_ * S_;
  const float* vb = v + (size_t)bh * S_ * HD_;
  float c[4][4] = {};
  const int srow = tid & 63, sk = (tid >> 6) * 8;     // A staging
  const int vr = tid >> 3, vd0 = (tid & 7) * 8;       // B staging
  for (int t0 = 0; t0 < S_; t0 += 32) {
    const float* app = ab + (size_t)(s0 + srow) * S_ + t0 + sk;
    float4 fa0 = *reinterpret_cast<const float4*>(app);
    float4 fa1 = *reinterpret_cast<const float4*>(app + 4);
    const float* vpp = vb + (size_t)(t0 + vr) * HD_ + vd0;
    float4 fv0 = *reinterpret_cast<const float4*>(vpp);
    float4 fv1 = *reinterpret_cast<const float4*>(vpp + 4);
    __syncthreads();
    As[sk + 0][srow] = fa0.x; As[sk + 1][srow] = fa0.y;
    As[sk + 2][srow] = fa0.z; As[sk + 3][srow] = fa0.w;
    As[sk + 4][srow] = fa1.x; As[sk + 5][srow] = fa1.y;
    As[sk + 6][srow] = fa1.z; As[sk + 7][srow] = fa1.w;
    *reinterpret_cast<float4*>(&Bs[vr][vd0]) = fv0;
    *reinterpret_cast<float4*>(&Bs[vr][vd0 + 4]) = fv1;
    __syncthreads();
#pragma unroll 8
    for (int kk = 0; kk < 32; ++kk) {
      const float4 a4 = *reinterpret_cast<const float4*>(&As[kk][ty * 4]);
      const float4 b4 = *reinterpret_cast<const float4*>(&Bs[kk][tx * 4]);
      const float a[4] = {a4.x, a4.y, a4.z, a4.w};
      const float bb[4] = {b4.x, b4.y, b4.z, b4.w};
#pragma unroll
      for (int i = 0; i < 4; ++i)
#pragma unroll
        for (int j = 0; j < 4; ++j) c[i][j] = fmaf(a[i], bb[j], c[i][j]);
    }
  }
#pragma unroll
  for (int i = 0; i < 4; ++i) {
    const int ss = s0 + ty * 4 + i;
    float* dst = ao + (size_t)(b * S_ + ss) * D_ + h * HD_;
#pragma unroll
    for (int j = 0; j < 4; ++j) dst[tx * 4 + j] = c[i][j];
  }
}

// ---------------------------------------------------------------------------
// K8: y = ao @ out_w^T + out_b  -> f32 d_out   (k-major LDS, b128 reads)
// ---------------------------------------------------------------------------
__global__ __launch_bounds__(256) void k_gemm_out(
    const float* __restrict__ a, const float* __restrict__ w,
    const float* __restrict__ bias, float* __restrict__ y) {
  __shared__ float As[32][68];
  __shared__ float Bs[32][68];
  const int tid = threadIdx.x;
  const int m0 = blockIdx.y * 64;
  const int n0 = blockIdx.x * 64;
  const int tx = tid & 15, ty = tid >> 4;
  const int srow = tid & 63, sk = (tid >> 6) * 8;
  float c[4][4] = {};
  for (int k0 = 0; k0 < D_; k0 += 32) {
    const float* apx = a + (size_t)(m0 + srow) * D_ + k0 + sk;
    const float* wpx = w + (size_t)(n0 + srow) * D_ + k0 + sk;
    float4 fa0 = *reinterpret_cast<const float4*>(apx);
    float4 fa1 = *reinterpret_cast<const float4*>(apx + 4);
    float4 fb0 = *reinterpret_cast<const float4*>(wpx);
    float4 fb1 = *reinterpret_cast<const float4*>(wpx + 4);
    __syncthreads();
    As[sk + 0][srow] = fa0.x; As[sk + 1][srow] = fa0.y;
    As[sk + 2][srow] = fa0.z; As[sk + 3][srow] = fa0.w;
    As[sk + 4][srow] = fa1.x; As[sk + 5][srow] = fa1.y;
    As[sk + 6][srow] = fa1.z; As[sk + 7][srow] = fa1.w;
    Bs[sk + 0][srow] = fb0.x; Bs[sk + 1][srow] = fb0.y;
    Bs[sk + 2][srow] = fb0.z; Bs[sk + 3][srow] = fb0.w;
    Bs[sk + 4][srow] = fb1.x; Bs[sk + 5][srow] = fb1.y;
    Bs[sk + 6][srow] = fb1.z; Bs[sk + 7][srow] = fb1.w;
    __syncthreads();
#pragma unroll 8
    for (int kk = 0; kk < 32; ++kk) {
      const float4 a4 = *reinterpret_cast<const float4*>(&As[kk][ty * 4]);
      const float4 b4 = *reinterpret_cast<const float4*>(&Bs[kk][tx * 4]);
      const float av[4] = {a4.x, a4.y, a4.z, a4.w};
      const float bv[4] = {b4.x, b4.y, b4.z, b4.w};
#pragma unroll
      for (int i = 0; i < 4; ++i)
#pragma unroll
        for (int j = 0; j < 4; ++j) c[i][j] = fmaf(av[i], bv[j], c[i][j]);
    }
  }
#pragma unroll
  for (int j = 0; j < 4; ++j) {
    const int n = n0 + tx * 4 + j;
    const float bb = bias[n];
#pragma unroll
    for (int i = 0; i < 4; ++i) {
      const int m = m0 + ty * 4 + i;
      y[(size_t)m * D_ + n] = c[i][j] + bb;
    }
  }
}

extern "C" void kernel_launch(void* const* d_in, const int* in_sizes, int n_in,
                              void* d_out, int out_size, void* d_ws, size_t ws_size,
                              hipStream_t stream) {
  const float* x = (const float*)d_in[0];
  const float* qkv_w = (const float*)d_in[1];
  const float* qkv_b = (const float*)d_in[2];
  const float* out_w = (const float*)d_in[3];
  const float* out_b = (const float*)d_in[4];

  constexpr size_t QN = (size_t)BH_ * S_ * HD_;  // 4,194,304
  float* ws = (float*)d_ws;
  float* q = ws;
  float* kbuf = q + QN;
  float* vbuf = kbuf + QN;
  float* ao = vbuf + QN;                 // (B,S,D) f32
  float* d2c = ao + QN;                  // (BH,S)
  float* sqn = d2c + BH_ * S_;
  float* mmd = sqn + BH_ * S_;
  float* d2cmax = mmd + BH_ * S_;        // (BH)
  float* mmdmax = d2cmax + BH_;
  unsigned char* lmask = (unsigned char*)(mmdmax + BH_);  // (BH,S) bytes

  float* outy = (float*)d_out;           // (B,S,D) f32
  float* attn = outy + QN;               // (BH,S,S) f32

  k_gemm_qkv<<<dim3(48, 64), dim3(256), 0, stream>>>(x, qkv_w, qkv_b, q, kbuf, vbuf);
  k_centroid<<<dim3(32), dim3(256), 0, stream>>>(x, d2c, sqn, d2cmax);
  k_kth<<<dim3(64, 32), dim3(256), 0, stream>>>(x, sqn, mmd);
  k_maxreduce<<<dim3(32), dim3(256), 0, stream>>>(mmd, mmdmax);
  k_topk<<<dim3(32), dim3(256), 0, stream>>>(d2c, mmd, d2cmax, mmdmax, lmask);
  k_attn<<<dim3(1024), dim3(256), 0, stream>>>(q, kbuf, lmask, attn);
  k_av<<<dim3(32, 32), dim3(256), 0, stream>>>(attn, vbuf, ao);
  k_gemm_out<<<dim3(16, 64), dim3(256), 0, stream>>>(ao, out_w, out_b, outy);
}

// Round 4
// 9815.763 us; speedup vs baseline: 1.0082x; 1.0082x over previous
//
#include <hip/hip_runtime.h>
#include <hip/hip_bf16.h>

#define DI __device__ __forceinline__

constexpr int S_ = 2048;
constexpr int D_ = 1024;
constexpr int H_ = 16;
constexpr int HD_ = 64;
constexpr int BH_ = 32;      // B*H
constexpr int NKEEP = 675;   // max(int(2048*0.33), 2)

DI float wsum(float v) {
#pragma unroll
  for (int o = 32; o > 0; o >>= 1) v += __shfl_xor(v, o, 64);
  return v;
}
DI float wmaxr(float v) {
#pragma unroll
  for (int o = 32; o > 0; o >>= 1) v = fmaxf(v, __shfl_xor(v, o, 64));
  return v;
}
DI float wminr(float v) {
#pragma unroll
  for (int o = 32; o > 0; o >>= 1) v = fminf(v, __shfl_xor(v, o, 64));
  return v;
}

// ---------------------------------------------------------------------------
// K1: qkv = x @ qkv_w^T + qkv_b, scattered to q/k/v (B,H,S,64) f32
// k-major LDS tiles -> inner loop is 2x ds_read_b128 + 16 FMA per kk.
// ---------------------------------------------------------------------------
__global__ __launch_bounds__(256) void k_gemm_qkv(
    const float* __restrict__ x, const float* __restrict__ w,
    const float* __restrict__ bias, float* __restrict__ q,
    float* __restrict__ kbuf, float* __restrict__ vbuf) {
  __shared__ float As[32][68];   // As[k][m]
  __shared__ float Bs[32][68];   // Bs[k][n]
  const int tid = threadIdx.x;
  const int m0 = blockIdx.y * 64;
  const int n0 = blockIdx.x * 64;
  const int tx = tid & 15, ty = tid >> 4;
  const int srow = tid & 63, sk = (tid >> 6) * 8;
  float c[4][4] = {};
  for (int k0 = 0; k0 < D_; k0 += 32) {
    const float* xp = x + (size_t)(m0 + srow) * D_ + k0 + sk;
    const float* wp = w + (size_t)(n0 + srow) * D_ + k0 + sk;
    float4 fa0 = *reinterpret_cast<const float4*>(xp);
    float4 fa1 = *reinterpret_cast<const float4*>(xp + 4);
    float4 fb0 = *reinterpret_cast<const float4*>(wp);
    float4 fb1 = *reinterpret_cast<const float4*>(wp + 4);
    __syncthreads();
    As[sk + 0][srow] = fa0.x; As[sk + 1][srow] = fa0.y;
    As[sk + 2][srow] = fa0.z; As[sk + 3][srow] = fa0.w;
    As[sk + 4][srow] = fa1.x; As[sk + 5][srow] = fa1.y;
    As[sk + 6][srow] = fa1.z; As[sk + 7][srow] = fa1.w;
    Bs[sk + 0][srow] = fb0.x; Bs[sk + 1][srow] = fb0.y;
    Bs[sk + 2][srow] = fb0.z; Bs[sk + 3][srow] = fb0.w;
    Bs[sk + 4][srow] = fb1.x; Bs[sk + 5][srow] = fb1.y;
    Bs[sk + 6][srow] = fb1.z; Bs[sk + 7][srow] = fb1.w;
    __syncthreads();
#pragma unroll 8
    for (int kk = 0; kk < 32; ++kk) {
      const float4 a4 = *reinterpret_cast<const float4*>(&As[kk][ty * 4]);
      const float4 b4 = *reinterpret_cast<const float4*>(&Bs[kk][tx * 4]);
      const float a[4] = {a4.x, a4.y, a4.z, a4.w};
      const float b[4] = {b4.x, b4.y, b4.z, b4.w};
#pragma unroll
      for (int i = 0; i < 4; ++i)
#pragma unroll
        for (int j = 0; j < 4; ++j) c[i][j] = fmaf(a[i], b[j], c[i][j]);
    }
  }
#pragma unroll
  for (int j = 0; j < 4; ++j) {
    const int n = n0 + tx * 4 + j;
    const float bb = bias[n];
    const int which = n >> 10, rem = n & 1023;
    const int hh = rem >> 6, dd = rem & 63;
    float* dst = (which == 0) ? q : (which == 1) ? kbuf : vbuf;
#pragma unroll
    for (int i = 0; i < 4; ++i) {
      const int m = m0 + ty * 4 + i;
      const int bb2 = m >> 11, ss = m & (S_ - 1);
      dst[(((size_t)(bb2 * H_ + hh)) * S_ + ss) * HD_ + dd] = c[i][j] + bb;
    }
  }
}

// ---------------------------------------------------------------------------
// K2: per (b,h): centroid, d2c[s], sq[s], d2cmax
// ---------------------------------------------------------------------------
__global__ __launch_bounds__(256) void k_centroid(
    const float* __restrict__ x, float* __restrict__ d2c,
    float* __restrict__ sqn, float* __restrict__ d2cmax) {
  const int bh = blockIdx.x, b = bh >> 4, h = bh & 15;
  const int tid = threadIdx.x;
  const int d = tid & 63, w = tid >> 6;
  __shared__ float cpart[4][64];
  __shared__ float cent[64];
  __shared__ float wmax[4];
  const float* xb = x + (size_t)b * S_ * D_ + h * HD_;
  float part = 0.f;
  for (int s = w; s < S_; s += 4) part += xb[(size_t)s * D_ + d];
  cpart[w][d] = part;
  __syncthreads();
  if (tid < 64)
    cent[tid] = (cpart[0][tid] + cpart[1][tid] + cpart[2][tid] + cpart[3][tid]) * (1.f / 2048.f);
  __syncthreads();
  const float cd = cent[d];
  float lmax = 0.f;
  for (int s = w; s < S_; s += 4) {
    float val = xb[(size_t)s * D_ + d];
    float df = val - cd;
    float s1 = wsum(df * df);
    float s2 = wsum(val * val);
    if (d == 0) {
      float r = sqrtf(s1);
      d2c[bh * S_ + s] = r;
      sqn[bh * S_ + s] = s2;
      lmax = fmaxf(lmax, r);
    }
  }
  if (d == 0) wmax[w] = lmax;
  __syncthreads();
  if (tid == 0) d2cmax[bh] = fmaxf(fmaxf(wmax[0], wmax[1]), fmaxf(wmax[2], wmax[3]));
}

// branch-free sorted insert (ascending top[0..9])
DI void insert10(float* top, float v) {
#pragma unroll
  for (int j = 9; j >= 1; --j) top[j] = fmaxf(fminf(v, top[j]), top[j - 1]);
  top[0] = fminf(v, top[0]);
}

// ---------------------------------------------------------------------------
// K3: per row s: mmd[s] = sqrt(10th-smallest of clamp(sq_s+sq_t-2*dot,0))
// R=4 rows/wave (top[4][10]=40 VGPR, no spill), C=4 cands/lane,
// 16 rows/block, key tile 256x64 staged in [68]-stride LDS (conflict-free
// b128). grid (128, 32). Ascending-dd FMA chain -> bit-identical distances;
// selection is value-multiset -> mapping-independent.
// ---------------------------------------------------------------------------
__global__ __launch_bounds__(256) void k_kth(
    const float* __restrict__ x, const float* __restrict__ sqn,
    float* __restrict__ mmd) {
  const int bh = blockIdx.y, b = bh >> 4, h = bh & 15;
  const int s0 = blockIdx.x * 16;
  const int tid = threadIdx.x;
  const int w = tid >> 6, lane = tid & 63;
  __shared__ float Xt[256][68];     // 69.6 KB key tile
  __shared__ float sRow[16][68];    // 4.3 KB q rows
  __shared__ float sq16[16];
  const float* xb = x + (size_t)b * S_ * D_ + h * HD_;
  // stage the 16 q-rows: 16x64 floats, 4 per thread
  {
    const int r = tid >> 4, c4 = (tid & 15) * 4;
    float4 f = *reinterpret_cast<const float4*>(xb + (size_t)(s0 + r) * D_ + c4);
    *reinterpret_cast<float4*>(&sRow[r][c4]) = f;
  }
  if (tid < 16) sq16[tid] = sqn[bh * S_ + s0 + tid];
  float top[4][10];
#pragma unroll
  for (int r = 0; r < 4; ++r)
#pragma unroll
    for (int i = 0; i < 10; ++i) top[r][i] = __builtin_inff();
  const int r0 = w * 4;
  for (int t0 = 0; t0 < S_; t0 += 256) {
    __syncthreads();
    // stage 256 key rows: 4096 float4, 16 per thread
#pragma unroll
    for (int it = 0; it < 16; ++it) {
      const int g = it * 256 + tid;
      const int rr = g >> 4, d0 = (g & 15) * 4;
      float4 f = *reinterpret_cast<const float4*>(xb + (size_t)(t0 + rr) * D_ + d0);
      *reinterpret_cast<float4*>(&Xt[rr][d0]) = f;
    }
    __syncthreads();
    float acc[4][4] = {};
    for (int d4 = 0; d4 < 64; d4 += 4) {
      float4 kv[4];
#pragma unroll
      for (int c = 0; c < 4; ++c)
        kv[c] = *reinterpret_cast<const float4*>(&Xt[c * 64 + lane][d4]);
#pragma unroll
      for (int r = 0; r < 4; ++r) {
        const float4 qv = *reinterpret_cast<const float4*>(&sRow[r0 + r][d4]);
#pragma unroll
        for (int c = 0; c < 4; ++c)
          acc[r][c] = fmaf(qv.w, kv[c].w, fmaf(qv.z, kv[c].z,
                        fmaf(qv.y, kv[c].y, fmaf(qv.x, kv[c].x, acc[r][c]))));
      }
    }
    float sqc[4];
#pragma unroll
    for (int c = 0; c < 4; ++c) sqc[c] = sqn[bh * S_ + t0 + c * 64 + lane];
#pragma unroll
    for (int r = 0; r < 4; ++r) {
      const float sq_s = sq16[r0 + r];
#pragma unroll
      for (int c = 0; c < 4; ++c) {
        const float v = fmaxf(sq_s + sqc[c] - 2.f * acc[r][c], 0.f);
        if (v < top[r][9]) insert10(top[r], v);
      }
    }
  }
  // wave-level multiset merge per row: extract global 10 smallest
#pragma unroll
  for (int r = 0; r < 4; ++r) {
    float kth = 0.f;
    for (int it = 0; it < 10; ++it) {
      const float mn = wminr(top[r][0]);
      unsigned long long ball = __ballot(top[r][0] == mn);
      const int src = __ffsll(ball) - 1;
      if (lane == src) {
#pragma unroll
        for (int j = 0; j < 9; ++j) top[r][j] = top[r][j + 1];
        top[r][9] = __builtin_inff();
      }
      kth = mn;
    }
    if (lane == 0) mmd[bh * S_ + s0 + r0 + r] = sqrtf(kth);
  }
}

// ---------------------------------------------------------------------------
// K4: per (b,h) max over mmd
// ---------------------------------------------------------------------------
__global__ __launch_bounds__(256) void k_maxreduce(
    const float* __restrict__ src, float* __restrict__ dst) {
  const int bh = blockIdx.x, tid = threadIdx.x;
  float m = 0.f;
  for (int s = tid; s < S_; s += 256) m = fmaxf(m, src[bh * S_ + s]);
  __shared__ float red[256];
  red[tid] = m;
  __syncthreads();
  for (int o = 128; o > 0; o >>= 1) {
    if (tid < o) red[tid] = fmaxf(red[tid], red[tid + o]);
    __syncthreads();
  }
  if (tid == 0) dst[bh] = red[0];
}

// ---------------------------------------------------------------------------
// K5: tls = 0.7*d2c/(d2cmax+1e-8) + 0.3*mmd/(mmdmax+1e-8); top-675 -> mask
// index-stable tie-break matching jax.lax.top_k
// ---------------------------------------------------------------------------
__global__ __launch_bounds__(256) void k_topk(
    const float* __restrict__ d2c, const float* __restrict__ mmd,
    const float* __restrict__ d2cmax, const float* __restrict__ mmdmax,
    unsigned char* __restrict__ lmask) {
  const int bh = blockIdx.x, tid = threadIdx.x;
  __shared__ float vals[S_];
  __shared__ int red[256];
  const float dden = d2cmax[bh] + 1e-8f;
  const float mden = mmdmax[bh] + 1e-8f;
  for (int s = tid; s < S_; s += 256) {
    float lift = d2c[bh * S_ + s] / dden;
    float mn = mmd[bh * S_ + s] / mden;
    vals[s] = 0.7f * lift + 0.3f * mn;
  }
  __syncthreads();
  // binary search on float bits (all vals >= 0) for the 675th largest value
  unsigned lo = 0u, hi = 0x7f800000u;
  while (hi - lo > 1u) {
    unsigned mid = (lo + hi) >> 1;
    float T = __uint_as_float(mid);
    int cc = 0;
    for (int s = tid; s < S_; s += 256) cc += (vals[s] >= T);
    red[tid] = cc;
    __syncthreads();
    for (int o = 128; o > 0; o >>= 1) {
      if (tid < o) red[tid] += red[tid + o];
      __syncthreads();
    }
    int cnt = red[0];
    __syncthreads();
    if (cnt >= NKEEP) lo = mid; else hi = mid;
  }
  const float v675 = __uint_as_float(lo);
  int cc = 0;
  for (int s = tid; s < S_; s += 256) cc += (vals[s] > v675);
  red[tid] = cc;
  __syncthreads();
  for (int o = 128; o > 0; o >>= 1) {
    if (tid < o) red[tid] += red[tid + o];
    __syncthreads();
  }
  const int need = NKEEP - red[0];
  __syncthreads();
  for (int s = tid; s < S_; s += 256) {
    float vv = vals[s];
    int sel = vv > v675;
    if (!sel && vv == v675) {
      int r = 0;
      for (int t = 0; t < s; ++t) r += (vals[t] == v675);
      sel = (r < need);
    }
    lmask[bh * S_ + s] = (unsigned char)sel;
  }
}

// ---------------------------------------------------------------------------
// K6: scores + mask + softmax -> attn.  Flash-style two-pass.
// ---------------------------------------------------------------------------
__global__ __launch_bounds__(256, 3) void k_attn(
    const float* __restrict__ q, const float* __restrict__ k,
    const unsigned char* __restrict__ lmask, float* __restrict__ attn) {
  const int bid = blockIdx.x;
  const int wg = (bid & 7) * 128 + (bid >> 3);   // bijective XCD swizzle (1024 = 8*128)
  const int bh = wg >> 5;
  const int s0 = (wg & 31) * 64;
  const int tid = threadIdx.x;
  const int tx = tid & 31, ty = tid >> 5;

  __shared__ float Qt[64][68];          // transposed: Qt[dd][row]
  __shared__ float Ks[128][65];         // Ks[col][dd]
  __shared__ unsigned char lm[S_];

  const float* qb = q + (size_t)bh * S_ * HD_;
  const float* kb = k + (size_t)bh * S_ * HD_;

  {
    const unsigned* lm32 = reinterpret_cast<const unsigned*>(lmask + bh * S_);
    unsigned* dl = reinterpret_cast<unsigned*>(lm);
    dl[tid] = lm32[tid];
    dl[tid + 256] = lm32[tid + 256];
#pragma unroll
    for (int it = 0; it < 4; ++it) {
      const int g = it * 256 + tid;
      const int r = g >> 4, d0 = (g & 15) * 4;
      float4 f = *reinterpret_cast<const float4*>(qb + (size_t)(s0 + r) * HD_ + d0);
      Qt[d0 + 0][r] = f.x; Qt[d0 + 1][r] = f.y;
      Qt[d0 + 2][r] = f.z; Qt[d0 + 3][r] = f.w;
    }
  }

  constexpr float SCL = 0.18033688011112042f;   // 0.125 * log2(e)
  constexpr float MB2 = -14426.950408889634f;   // -10000 * log2(e)

  const int row0 = ty * 8;
  const int col0 = tx * 4;
  const int rg0 = s0 + row0;

  float m[8], l[8], invl[8];
#pragma unroll
  for (int i = 0; i < 8; ++i) { m[i] = MB2; l[i] = 0.f; invl[i] = 0.f; }

  for (int pass = 0; pass < 2; ++pass) {
    for (int t = 0; t < 16; ++t) {
      const int t0 = t * 128;
      __syncthreads();
#pragma unroll
      for (int it = 0; it < 8; ++it) {
        const int g = it * 256 + tid;
        const int r = g >> 4, d0 = (g & 15) * 4;
        float4 f = *reinterpret_cast<const float4*>(kb + (size_t)(t0 + r) * HD_ + d0);
        Ks[r][d0 + 0] = f.x; Ks[r][d0 + 1] = f.y;
        Ks[r][d0 + 2] = f.z; Ks[r][d0 + 3] = f.w;
      }
      __syncthreads();

      float acc[8][4] = {};
      const float* ksp = &Ks[col0][0];
#pragma unroll 4
      for (int dd = 0; dd < 64; ++dd) {
        const float4 a0 = *reinterpret_cast<const float4*>(&Qt[dd][row0]);
        const float4 a1 = *reinterpret_cast<const float4*>(&Qt[dd][row0 + 4]);
        const float a[8] = {a0.x, a0.y, a0.z, a0.w, a1.x, a1.y, a1.z, a1.w};
        const float b[4] = {ksp[0 * 65 + dd], ksp[1 * 65 + dd],
                            ksp[2 * 65 + dd], ksp[3 * 65 + dd]};
#pragma unroll
        for (int i = 0; i < 8; ++i)
#pragma unroll
          for (int j = 0; j < 4; ++j) acc[i][j] = fmaf(a[i], b[j], acc[i][j]);
      }

      const int cg0 = t0 + col0;
      bool kc[4];
#pragma unroll
      for (int j = 0; j < 4; ++j) kc[j] = lm[cg0 + j] != 0;

      if (pass == 0) {
#pragma unroll
        for (int i = 0; i < 8; ++i) {
          const int rel0 = cg0 - (rg0 + i) + 64;   // keep iff 0 <= rel0+j <= 128
          float s[4];
#pragma unroll
          for (int j = 0; j < 4; ++j) {
            const bool kp = kc[j] || ((unsigned)(rel0 + j) <= 128u);
            s[j] = kp ? acc[i][j] * SCL : MB2;
          }
          const float tm = fmaxf(fmaxf(s[0], s[1]), fmaxf(s[2], s[3]));
          const float nm = fmaxf(m[i], tm);
          const float add = exp2f(s[0] - nm) + exp2f(s[1] - nm) +
                            exp2f(s[2] - nm) + exp2f(s[3] - nm);
          l[i] = l[i] * exp2f(m[i] - nm) + add;
          m[i] = nm;
        }
      } else {
        float* ap = attn + ((size_t)bh * S_ + rg0) * S_ + cg0;
#pragma unroll
        for (int i = 0; i < 8; ++i) {
          const int rel0 = cg0 - (rg0 + i) + 64;
          float o[4];
#pragma unroll
          for (int j = 0; j < 4; ++j) {
            const bool kp = kc[j] || ((unsigned)(rel0 + j) <= 128u);
            o[j] = kp ? exp2f(acc[i][j] * SCL - m[i]) * invl[i] : 0.f;
          }
          *reinterpret_cast<float4*>(ap + (size_t)i * S_) =
              make_float4(o[0], o[1], o[2], o[3]);
        }
      }
    }
    if (pass == 0) {
#pragma unroll
      for (int i = 0; i < 8; ++i) {
        float mi = m[i], li = l[i];
#pragma unroll
        for (int off = 1; off <= 16; off <<= 1) {
          const float om = __shfl_xor(mi, off, 64);
          const float ol = __shfl_xor(li, off, 64);
          const float nm = fmaxf(mi, om);
          li = li * exp2f(mi - nm) + ol * exp2f(om - nm);
          mi = nm;
        }
        m[i] = mi; l[i] = li; invl[i] = 1.f / li;
      }
    }
  }
}

// ---------------------------------------------------------------------------
// K7: ao(b,s,h*64+d) = attn(bh,s,:) @ v(bh,:,d)   k-major LDS, b128 reads
// ---------------------------------------------------------------------------
__global__ __launch_bounds__(256) void k_av(
    const float* __restrict__ attn, const float* __restrict__ v,
    float* __restrict__ ao) {
  const int bh = blockIdx.y, b = bh >> 4, h = bh & 15;
  const int s0 = blockIdx.x * 64;
  const int tid = threadIdx.x, tx = tid & 15, ty = tid >> 4;
  __shared__ float As[32][68];   // As[k][s]
  __shared__ float Bs[32][68];   // Bs[k][d]
  const float* ab = attn + (size_t)bh * S_ * S_;
  const float* vb = v + (size_t)bh * S_ * HD_;
  float c[4][4] = {};
  const int srow = tid & 63, sk = (tid >> 6) * 8;     // A staging
  const int vr = tid >> 3, vd0 = (tid & 7) * 8;       // B staging
  for (int t0 = 0; t0 < S_; t0 += 32) {
    const float* app = ab + (size_t)(s0 + srow) * S_ + t0 + sk;
    float4 fa0 = *reinterpret_cast<const float4*>(app);
    float4 fa1 = *reinterpret_cast<const float4*>(app + 4);
    const float* vpp = vb + (size_t)(t0 + vr) * HD_ + vd0;
    float4 fv0 = *reinterpret_cast<const float4*>(vpp);
    float4 fv1 = *reinterpret_cast<const float4*>(vpp + 4);
    __syncthreads();
    As[sk + 0][srow] = fa0.x; As[sk + 1][srow] = fa0.y;
    As[sk + 2][srow] = fa0.z; As[sk + 3][srow] = fa0.w;
    As[sk + 4][srow] = fa1.x; As[sk + 5][srow] = fa1.y;
    As[sk + 6][srow] = fa1.z; As[sk + 7][srow] = fa1.w;
    *reinterpret_cast<float4*>(&Bs[vr][vd0]) = fv0;
    *reinterpret_cast<float4*>(&Bs[vr][vd0 + 4]) = fv1;
    __syncthreads();
#pragma unroll 8
    for (int kk = 0; kk < 32; ++kk) {
      const float4 a4 = *reinterpret_cast<const float4*>(&As[kk][ty * 4]);
      const float4 b4 = *reinterpret_cast<const float4*>(&Bs[kk][tx * 4]);
      const float a[4] = {a4.x, a4.y, a4.z, a4.w};
      const float bb[4] = {b4.x, b4.y, b4.z, b4.w};
#pragma unroll
      for (int i = 0; i < 4; ++i)
#pragma unroll
        for (int j = 0; j < 4; ++j) c[i][j] = fmaf(a[i], bb[j], c[i][j]);
    }
  }
#pragma unroll
  for (int i = 0; i < 4; ++i) {
    const int ss = s0 + ty * 4 + i;
    float* dst = ao + (size_t)(b * S_ + ss) * D_ + h * HD_;
#pragma unroll
    for (int j = 0; j < 4; ++j) dst[tx * 4 + j] = c[i][j];
  }
}

// ---------------------------------------------------------------------------
// K8: y = ao @ out_w^T + out_b  -> f32 d_out   (k-major LDS, b128 reads)
// ---------------------------------------------------------------------------
__global__ __launch_bounds__(256) void k_gemm_out(
    const float* __restrict__ a, const float* __restrict__ w,
    const float* __restrict__ bias, float* __restrict__ y) {
  __shared__ float As[32][68];
  __shared__ float Bs[32][68];
  const int tid = threadIdx.x;
  const int m0 = blockIdx.y * 64;
  const int n0 = blockIdx.x * 64;
  const int tx = tid & 15, ty = tid >> 4;
  const int srow = tid & 63, sk = (tid >> 6) * 8;
  float c[4][4] = {};
  for (int k0 = 0; k0 < D_; k0 += 32) {
    const float* apx = a + (size_t)(m0 + srow) * D_ + k0 + sk;
    const float* wpx = w + (size_t)(n0 + srow) * D_ + k0 + sk;
    float4 fa0 = *reinterpret_cast<const float4*>(apx);
    float4 fa1 = *reinterpret_cast<const float4*>(apx + 4);
    float4 fb0 = *reinterpret_cast<const float4*>(wpx);
    float4 fb1 = *reinterpret_cast<const float4*>(wpx + 4);
    __syncthreads();
    As[sk + 0][srow] = fa0.x; As[sk + 1][srow] = fa0.y;
    As[sk + 2][srow] = fa0.z; As[sk + 3][srow] = fa0.w;
    As[sk + 4][srow] = fa1.x; As[sk + 5][srow] = fa1.y;
    As[sk + 6][srow] = fa1.z; As[sk + 7][srow] = fa1.w;
    Bs[sk + 0][srow] = fb0.x; Bs[sk + 1][srow] = fb0.y;
    Bs[sk + 2][srow] = fb0.z; Bs[sk + 3][srow] = fb0.w;
    Bs[sk + 4][srow] = fb1.x; Bs[sk + 5][srow] = fb1.y;
    Bs[sk + 6][srow] = fb1.z; Bs[sk + 7][srow] = fb1.w;
    __syncthreads();
#pragma unroll 8
    for (int kk = 0; kk < 32; ++kk) {
      const float4 a4 = *reinterpret_cast<const float4*>(&As[kk][ty * 4]);
      const float4 b4 = *reinterpret_cast<const float4*>(&Bs[kk][tx * 4]);
      const float av[4] = {a4.x, a4.y, a4.z, a4.w};
      const float bv[4] = {b4.x, b4.y, b4.z, b4.w};
#pragma unroll
      for (int i = 0; i < 4; ++i)
#pragma unroll
        for (int j = 0; j < 4; ++j) c[i][j] = fmaf(av[i], bv[j], c[i][j]);
    }
  }
#pragma unroll
  for (int j = 0; j < 4; ++j) {
    const int n = n0 + tx * 4 + j;
    const float bb = bias[n];
#pragma unroll
    for (int i = 0; i < 4; ++i) {
      const int m = m0 + ty * 4 + i;
      y[(size_t)m * D_ + n] = c[i][j] + bb;
    }
  }
}

extern "C" void kernel_launch(void* const* d_in, const int* in_sizes, int n_in,
                              void* d_out, int out_size, void* d_ws, size_t ws_size,
                              hipStream_t stream) {
  const float* x = (const float*)d_in[0];
  const float* qkv_w = (const float*)d_in[1];
  const float* qkv_b = (const float*)d_in[2];
  const float* out_w = (const float*)d_in[3];
  const float* out_b = (const float*)d_in[4];

  constexpr size_t QN = (size_t)BH_ * S_ * HD_;  // 4,194,304
  float* ws = (float*)d_ws;
  float* q = ws;
  float* kbuf = q + QN;
  float* vbuf = kbuf + QN;
  float* ao = vbuf + QN;                 // (B,S,D) f32
  float* d2c = ao + QN;                  // (BH,S)
  float* sqn = d2c + BH_ * S_;
  float* mmd = sqn + BH_ * S_;
  float* d2cmax = mmd + BH_ * S_;        // (BH)
  float* mmdmax = d2cmax + BH_;
  unsigned char* lmask = (unsigned char*)(mmdmax + BH_);  // (BH,S) bytes

  float* outy = (float*)d_out;           // (B,S,D) f32
  float* attn = outy + QN;               // (BH,S,S) f32

  k_gemm_qkv<<<dim3(48, 64), dim3(256), 0, stream>>>(x, qkv_w, qkv_b, q, kbuf, vbuf);
  k_centroid<<<dim3(32), dim3(256), 0, stream>>>(x, d2c, sqn, d2cmax);
  k_kth<<<dim3(128, 32), dim3(256), 0, stream>>>(x, sqn, mmd);
  k_maxreduce<<<dim3(32), dim3(256), 0, stream>>>(mmd, mmdmax);
  k_topk<<<dim3(32), dim3(256), 0, stream>>>(d2c, mmd, d2cmax, mmdmax, lmask);
  k_attn<<<dim3(1024), dim3(256), 0, stream>>>(q, kbuf, lmask, attn);
  k_av<<<dim3(32, 32), dim3(256), 0, stream>>>(attn, vbuf, ao);
  k_gemm_out<<<dim3(16, 64), dim3(256), 0, stream>>>(ao, out_w, out_b, outy);
}

// Round 6
// 5633.167 us; speedup vs baseline: 1.7568x; 1.7425x over previous
//
#include <hip/hip_runtime.h>
#include <hip/hip_bf16.h>

#define DI __device__ __forceinline__

constexpr int S_ = 2048;
constexpr int D_ = 1024;
constexpr int H_ = 16;
constexpr int HD_ = 64;
constexpr int BH_ = 32;      // B*H
constexpr int NKEEP = 675;   // max(int(2048*0.33), 2)

DI float wsum(float v) {
#pragma unroll
  for (int o = 32; o > 0; o >>= 1) v += __shfl_xor(v, o, 64);
  return v;
}
DI float wmaxr(float v) {
#pragma unroll
  for (int o = 32; o > 0; o >>= 1) v = fmaxf(v, __shfl_xor(v, o, 64));
  return v;
}
DI float wminr(float v) {
#pragma unroll
  for (int o = 32; o > 0; o >>= 1) v = fminf(v, __shfl_xor(v, o, 64));
  return v;
}

// ---------------------------------------------------------------------------
// K1: qkv = x @ qkv_w^T + qkv_b, scattered to q/k/v (B,H,S,64) f32
// k-major LDS tiles -> inner loop is 2x ds_read_b128 + 16 FMA per kk.
// ---------------------------------------------------------------------------
__global__ __launch_bounds__(256) void k_gemm_qkv(
    const float* __restrict__ x, const float* __restrict__ w,
    const float* __restrict__ bias, float* __restrict__ q,
    float* __restrict__ kbuf, float* __restrict__ vbuf) {
  __shared__ float As[32][68];   // As[k][m]
  __shared__ float Bs[32][68];   // Bs[k][n]
  const int tid = threadIdx.x;
  const int m0 = blockIdx.y * 64;
  const int n0 = blockIdx.x * 64;
  const int tx = tid & 15, ty = tid >> 4;
  const int srow = tid & 63, sk = (tid >> 6) * 8;
  float c[4][4] = {};
  for (int k0 = 0; k0 < D_; k0 += 32) {
    const float* xp = x + (size_t)(m0 + srow) * D_ + k0 + sk;
    const float* wp = w + (size_t)(n0 + srow) * D_ + k0 + sk;
    float4 fa0 = *reinterpret_cast<const float4*>(xp);
    float4 fa1 = *reinterpret_cast<const float4*>(xp + 4);
    float4 fb0 = *reinterpret_cast<const float4*>(wp);
    float4 fb1 = *reinterpret_cast<const float4*>(wp + 4);
    __syncthreads();
    As[sk + 0][srow] = fa0.x; As[sk + 1][srow] = fa0.y;
    As[sk + 2][srow] = fa0.z; As[sk + 3][srow] = fa0.w;
    As[sk + 4][srow] = fa1.x; As[sk + 5][srow] = fa1.y;
    As[sk + 6][srow] = fa1.z; As[sk + 7][srow] = fa1.w;
    Bs[sk + 0][srow] = fb0.x; Bs[sk + 1][srow] = fb0.y;
    Bs[sk + 2][srow] = fb0.z; Bs[sk + 3][srow] = fb0.w;
    Bs[sk + 4][srow] = fb1.x; Bs[sk + 5][srow] = fb1.y;
    Bs[sk + 6][srow] = fb1.z; Bs[sk + 7][srow] = fb1.w;
    __syncthreads();
#pragma unroll 8
    for (int kk = 0; kk < 32; ++kk) {
      const float4 a4 = *reinterpret_cast<const float4*>(&As[kk][ty * 4]);
      const float4 b4 = *reinterpret_cast<const float4*>(&Bs[kk][tx * 4]);
      const float a[4] = {a4.x, a4.y, a4.z, a4.w};
      const float b[4] = {b4.x, b4.y, b4.z, b4.w};
#pragma unroll
      for (int i = 0; i < 4; ++i)
#pragma unroll
        for (int j = 0; j < 4; ++j) c[i][j] = fmaf(a[i], b[j], c[i][j]);
    }
  }
#pragma unroll
  for (int j = 0; j < 4; ++j) {
    const int n = n0 + tx * 4 + j;
    const float bb = bias[n];
    const int which = n >> 10, rem = n & 1023;
    const int hh = rem >> 6, dd = rem & 63;
    float* dst = (which == 0) ? q : (which == 1) ? kbuf : vbuf;
#pragma unroll
    for (int i = 0; i < 4; ++i) {
      const int m = m0 + ty * 4 + i;
      const int bb2 = m >> 11, ss = m & (S_ - 1);
      dst[(((size_t)(bb2 * H_ + hh)) * S_ + ss) * HD_ + dd] = c[i][j] + bb;
    }
  }
}

// ---------------------------------------------------------------------------
// K2: per (b,h): centroid, d2c[s], sq[s], d2cmax
// ---------------------------------------------------------------------------
__global__ __launch_bounds__(256) void k_centroid(
    const float* __restrict__ x, float* __restrict__ d2c,
    float* __restrict__ sqn, float* __restrict__ d2cmax) {
  const int bh = blockIdx.x, b = bh >> 4, h = bh & 15;
  const int tid = threadIdx.x;
  const int d = tid & 63, w = tid >> 6;
  __shared__ float cpart[4][64];
  __shared__ float cent[64];
  __shared__ float wmax[4];
  const float* xb = x + (size_t)b * S_ * D_ + h * HD_;
  float part = 0.f;
  for (int s = w; s < S_; s += 4) part += xb[(size_t)s * D_ + d];
  cpart[w][d] = part;
  __syncthreads();
  if (tid < 64)
    cent[tid] = (cpart[0][tid] + cpart[1][tid] + cpart[2][tid] + cpart[3][tid]) * (1.f / 2048.f);
  __syncthreads();
  const float cd = cent[d];
  float lmax = 0.f;
  for (int s = w; s < S_; s += 4) {
    float val = xb[(size_t)s * D_ + d];
    float df = val - cd;
    float s1 = wsum(df * df);
    float s2 = wsum(val * val);
    if (d == 0) {
      float r = sqrtf(s1);
      d2c[bh * S_ + s] = r;
      sqn[bh * S_ + s] = s2;
      lmax = fmaxf(lmax, r);
    }
  }
  if (d == 0) wmax[w] = lmax;
  __syncthreads();
  if (tid == 0) d2cmax[bh] = fmaxf(fmaxf(wmax[0], wmax[1]), fmaxf(wmax[2], wmax[3]));
}

// ---------------------------------------------------------------------------
// K3: per row s: mmd[s] = sqrt(10th-smallest of clamp(sq_s+sq_t-2*dot,0))
// R=4 rows/wave x C=4 cands/lane, 16 rows/block, 256-row key tile in
// [68]-stride LDS (conflict-free b128). Top-10 lists are 40 NAMED scalars
// (macros, compile-time fields only) -> SROA-proof, no scratch.
// Same fmin/fmax insert network and ascending-dd FMA chain as the verified
// v1 -> bit-identical mmd.
// ---------------------------------------------------------------------------
#define TOP_DECL(p)                                                          \
  float p##0 = __builtin_inff(), p##1 = __builtin_inff(),                    \
        p##2 = __builtin_inff(), p##3 = __builtin_inff(),                    \
        p##4 = __builtin_inff(), p##5 = __builtin_inff(),                    \
        p##6 = __builtin_inff(), p##7 = __builtin_inff(),                    \
        p##8 = __builtin_inff(), p##9 = __builtin_inff()

#define INS10(p, v)                                                          \
  if ((v) < p##9) {                                                          \
    p##9 = fmaxf(fminf((v), p##9), p##8);                                    \
    p##8 = fmaxf(fminf((v), p##8), p##7);                                    \
    p##7 = fmaxf(fminf((v), p##7), p##6);                                    \
    p##6 = fmaxf(fminf((v), p##6), p##5);                                    \
    p##5 = fmaxf(fminf((v), p##5), p##4);                                    \
    p##4 = fmaxf(fminf((v), p##4), p##3);                                    \
    p##3 = fmaxf(fminf((v), p##3), p##2);                                    \
    p##2 = fmaxf(fminf((v), p##2), p##1);                                    \
    p##1 = fmaxf(fminf((v), p##1), p##0);                                    \
    p##0 = fminf((v), p##0);                                                 \
  }

#define ROW_INS(p, ri)                                                       \
  {                                                                          \
    const float sq_s = sq16[r0 + (ri)];                                      \
    { const float vv = fmaxf(sq_s + sqc[0] - 2.f * acc[ri][0], 0.f); INS10(p, vv); } \
    { const float vv = fmaxf(sq_s + sqc[1] - 2.f * acc[ri][1], 0.f); INS10(p, vv); } \
    { const float vv = fmaxf(sq_s + sqc[2] - 2.f * acc[ri][2], 0.f); INS10(p, vv); } \
    { const float vv = fmaxf(sq_s + sqc[3] - 2.f * acc[ri][3], 0.f); INS10(p, vv); } \
  }

#define MERGE10(p, outidx)                                                   \
  {                                                                          \
    float kth = 0.f;                                                         \
    for (int it = 0; it < 10; ++it) {                                        \
      const float mn = wminr(p##0);                                          \
      unsigned long long ball = __ballot(p##0 == mn);                        \
      const int src = __ffsll(ball) - 1;                                     \
      if (lane == src) {                                                     \
        p##0 = p##1; p##1 = p##2; p##2 = p##3; p##3 = p##4; p##4 = p##5;     \
        p##5 = p##6; p##6 = p##7; p##7 = p##8; p##8 = p##9;                  \
        p##9 = __builtin_inff();                                             \
      }                                                                      \
      kth = mn;                                                              \
    }                                                                        \
    if (lane == 0) mmd[bh * S_ + s0 + (outidx)] = sqrtf(kth);                \
  }

__global__ __launch_bounds__(256) void k_kth(
    const float* __restrict__ x, const float* __restrict__ sqn,
    float* __restrict__ mmd) {
  const int bh = blockIdx.y, b = bh >> 4, h = bh & 15;
  const int s0 = blockIdx.x * 16;
  const int tid = threadIdx.x;
  const int w = tid >> 6, lane = tid & 63;
  __shared__ float Xt[256][68];     // 69.6 KB key tile
  __shared__ float sRow[16][68];    // 4.3 KB q rows
  __shared__ float sq16[16];
  const float* xb = x + (size_t)b * S_ * D_ + h * HD_;
  // stage the 16 q-rows: 16x64 floats, 4 per thread
  {
    const int r = tid >> 4, c4 = (tid & 15) * 4;
    float4 f = *reinterpret_cast<const float4*>(xb + (size_t)(s0 + r) * D_ + c4);
    *reinterpret_cast<float4*>(&sRow[r][c4]) = f;
  }
  if (tid < 16) sq16[tid] = sqn[bh * S_ + s0 + tid];
  const int r0 = w * 4;
  TOP_DECL(t0_);
  TOP_DECL(t1_);
  TOP_DECL(t2_);
  TOP_DECL(t3_);
  for (int t0 = 0; t0 < S_; t0 += 256) {
    __syncthreads();
    // stage 256 key rows: 4096 float4, 16 per thread
#pragma unroll 4
    for (int it = 0; it < 16; ++it) {
      const int g = it * 256 + tid;
      const int rr = g >> 4, d0 = (g & 15) * 4;
      float4 f = *reinterpret_cast<const float4*>(xb + (size_t)(t0 + rr) * D_ + d0);
      *reinterpret_cast<float4*>(&Xt[rr][d0]) = f;
    }
    __syncthreads();
    float acc[4][4] = {};
#pragma unroll
    for (int d4 = 0; d4 < 64; d4 += 4) {
      float4 kv[4];
#pragma unroll
      for (int c = 0; c < 4; ++c)
        kv[c] = *reinterpret_cast<const float4*>(&Xt[c * 64 + lane][d4]);
#pragma unroll
      for (int r = 0; r < 4; ++r) {
        const float4 qv = *reinterpret_cast<const float4*>(&sRow[r0 + r][d4]);
#pragma unroll
        for (int c = 0; c < 4; ++c)
          acc[r][c] = fmaf(qv.w, kv[c].w, fmaf(qv.z, kv[c].z,
                        fmaf(qv.y, kv[c].y, fmaf(qv.x, kv[c].x, acc[r][c]))));
      }
    }
    float sqc[4];
#pragma unroll
    for (int c = 0; c < 4; ++c) sqc[c] = sqn[bh * S_ + t0 + c * 64 + lane];
    ROW_INS(t0_, 0);
    ROW_INS(t1_, 1);
    ROW_INS(t2_, 2);
    ROW_INS(t3_, 3);
  }
  // wave-level multiset merge per row: extract global 10 smallest
  MERGE10(t0_, r0 + 0);
  MERGE10(t1_, r0 + 1);
  MERGE10(t2_, r0 + 2);
  MERGE10(t3_, r0 + 3);
}

// ---------------------------------------------------------------------------
// K4: per (b,h) max over mmd
// ---------------------------------------------------------------------------
__global__ __launch_bounds__(256) void k_maxreduce(
    const float* __restrict__ src, float* __restrict__ dst) {
  const int bh = blockIdx.x, tid = threadIdx.x;
  float m = 0.f;
  for (int s = tid; s < S_; s += 256) m = fmaxf(m, src[bh * S_ + s]);
  __shared__ float red[256];
  red[tid] = m;
  __syncthreads();
  for (int o = 128; o > 0; o >>= 1) {
    if (tid < o) red[tid] = fmaxf(red[tid], red[tid + o]);
    __syncthreads();
  }
  if (tid == 0) dst[bh] = red[0];
}

// ---------------------------------------------------------------------------
// K5: tls = 0.7*d2c/(d2cmax+1e-8) + 0.3*mmd/(mmdmax+1e-8); top-675 -> mask
// index-stable tie-break matching jax.lax.top_k
// ---------------------------------------------------------------------------
__global__ __launch_bounds__(256) void k_topk(
    const float* __restrict__ d2c, const float* __restrict__ mmd,
    const float* __restrict__ d2cmax, const float* __restrict__ mmdmax,
    unsigned char* __restrict__ lmask) {
  const int bh = blockIdx.x, tid = threadIdx.x;
  __shared__ float vals[S_];
  __shared__ int red[256];
  const float dden = d2cmax[bh] + 1e-8f;
  const float mden = mmdmax[bh] + 1e-8f;
  for (int s = tid; s < S_; s += 256) {
    float lift = d2c[bh * S_ + s] / dden;
    float mn = mmd[bh * S_ + s] / mden;
    vals[s] = 0.7f * lift + 0.3f * mn;
  }
  __syncthreads();
  // binary search on float bits (all vals >= 0) for the 675th largest value
  unsigned lo = 0u, hi = 0x7f800000u;
  while (hi - lo > 1u) {
    unsigned mid = (lo + hi) >> 1;
    float T = __uint_as_float(mid);
    int cc = 0;
    for (int s = tid; s < S_; s += 256) cc += (vals[s] >= T);
    red[tid] = cc;
    __syncthreads();
    for (int o = 128; o > 0; o >>= 1) {
      if (tid < o) red[tid] += red[tid + o];
      __syncthreads();
    }
    int cnt = red[0];
    __syncthreads();
    if (cnt >= NKEEP) lo = mid; else hi = mid;
  }
  const float v675 = __uint_as_float(lo);
  int cc = 0;
  for (int s = tid; s < S_; s += 256) cc += (vals[s] > v675);
  red[tid] = cc;
  __syncthreads();
  for (int o = 128; o > 0; o >>= 1) {
    if (tid < o) red[tid] += red[tid + o];
    __syncthreads();
  }
  const int need = NKEEP - red[0];
  __syncthreads();
  for (int s = tid; s < S_; s += 256) {
    float vv = vals[s];
    int sel = vv > v675;
    if (!sel && vv == v675) {
      int r = 0;
      for (int t = 0; t < s; ++t) r += (vals[t] == v675);
      sel = (r < need);
    }
    lmask[bh * S_ + s] = (unsigned char)sel;
  }
}

// ---------------------------------------------------------------------------
// K6: scores + mask + softmax -> attn.  Flash-style two-pass.
// ---------------------------------------------------------------------------
__global__ __launch_bounds__(256, 3) void k_attn(
    const float* __restrict__ q, const float* __restrict__ k,
    const unsigned char* __restrict__ lmask, float* __restrict__ attn) {
  const int bid = blockIdx.x;
  const int wg = (bid & 7) * 128 + (bid >> 3);   // bijective XCD swizzle (1024 = 8*128)
  const int bh = wg >> 5;
  const int s0 = (wg & 31) * 64;
  const int tid = threadIdx.x;
  const int tx = tid & 31, ty = tid >> 5;

  __shared__ float Qt[64][68];          // transposed: Qt[dd][row]
  __shared__ float Ks[128][65];         // Ks[col][dd]
  __shared__ unsigned char lm[S_];

  const float* qb = q + (size_t)bh * S_ * HD_;
  const float* kb = k + (size_t)bh * S_ * HD_;

  {
    const unsigned* lm32 = reinterpret_cast<const unsigned*>(lmask + bh * S_);
    unsigned* dl = reinterpret_cast<unsigned*>(lm);
    dl[tid] = lm32[tid];
    dl[tid + 256] = lm32[tid + 256];
#pragma unroll
    for (int it = 0; it < 4; ++it) {
      const int g = it * 256 + tid;
      const int r = g >> 4, d0 = (g & 15) * 4;
      float4 f = *reinterpret_cast<const float4*>(qb + (size_t)(s0 + r) * HD_ + d0);
      Qt[d0 + 0][r] = f.x; Qt[d0 + 1][r] = f.y;
      Qt[d0 + 2][r] = f.z; Qt[d0 + 3][r] = f.w;
    }
  }

  constexpr float SCL = 0.18033688011112042f;   // 0.125 * log2(e)
  constexpr float MB2 = -14426.950408889634f;   // -10000 * log2(e)

  const int row0 = ty * 8;
  const int col0 = tx * 4;
  const int rg0 = s0 + row0;

  float m[8], l[8], invl[8];
#pragma unroll
  for (int i = 0; i < 8; ++i) { m[i] = MB2; l[i] = 0.f; invl[i] = 0.f; }

  for (int pass = 0; pass < 2; ++pass) {
    for (int t = 0; t < 16; ++t) {
      const int t0 = t * 128;
      __syncthreads();
#pragma unroll
      for (int it = 0; it < 8; ++it) {
        const int g = it * 256 + tid;
        const int r = g >> 4, d0 = (g & 15) * 4;
        float4 f = *reinterpret_cast<const float4*>(kb + (size_t)(t0 + r) * HD_ + d0);
        Ks[r][d0 + 0] = f.x; Ks[r][d0 + 1] = f.y;
        Ks[r][d0 + 2] = f.z; Ks[r][d0 + 3] = f.w;
      }
      __syncthreads();

      float acc[8][4] = {};
      const float* ksp = &Ks[col0][0];
#pragma unroll 4
      for (int dd = 0; dd < 64; ++dd) {
        const float4 a0 = *reinterpret_cast<const float4*>(&Qt[dd][row0]);
        const float4 a1 = *reinterpret_cast<const float4*>(&Qt[dd][row0 + 4]);
        const float a[8] = {a0.x, a0.y, a0.z, a0.w, a1.x, a1.y, a1.z, a1.w};
        const float b[4] = {ksp[0 * 65 + dd], ksp[1 * 65 + dd],
                            ksp[2 * 65 + dd], ksp[3 * 65 + dd]};
#pragma unroll
        for (int i = 0; i < 8; ++i)
#pragma unroll
          for (int j = 0; j < 4; ++j) acc[i][j] = fmaf(a[i], b[j], acc[i][j]);
      }

      const int cg0 = t0 + col0;
      bool kc[4];
#pragma unroll
      for (int j = 0; j < 4; ++j) kc[j] = lm[cg0 + j] != 0;

      if (pass == 0) {
#pragma unroll
        for (int i = 0; i < 8; ++i) {
          const int rel0 = cg0 - (rg0 + i) + 64;   // keep iff 0 <= rel0+j <= 128
          float s[4];
#pragma unroll
          for (int j = 0; j < 4; ++j) {
            const bool kp = kc[j] || ((unsigned)(rel0 + j) <= 128u);
            s[j] = kp ? acc[i][j] * SCL : MB2;
          }
          const float tm = fmaxf(fmaxf(s[0], s[1]), fmaxf(s[2], s[3]));
          const float nm = fmaxf(m[i], tm);
          const float add = exp2f(s[0] - nm) + exp2f(s[1] - nm) +
                            exp2f(s[2] - nm) + exp2f(s[3] - nm);
          l[i] = l[i] * exp2f(m[i] - nm) + add;
          m[i] = nm;
        }
      } else {
        float* ap = attn + ((size_t)bh * S_ + rg0) * S_ + cg0;
#pragma unroll
        for (int i = 0; i < 8; ++i) {
          const int rel0 = cg0 - (rg0 + i) + 64;
          float o[4];
#pragma unroll
          for (int j = 0; j < 4; ++j) {
            const bool kp = kc[j] || ((unsigned)(rel0 + j) <= 128u);
            o[j] = kp ? exp2f(acc[i][j] * SCL - m[i]) * invl[i] : 0.f;
          }
          *reinterpret_cast<float4*>(ap + (size_t)i * S_) =
              make_float4(o[0], o[1], o[2], o[3]);
        }
      }
    }
    if (pass == 0) {
#pragma unroll
      for (int i = 0; i < 8; ++i) {
        float mi = m[i], li = l[i];
#pragma unroll
        for (int off = 1; off <= 16; off <<= 1) {
          const float om = __shfl_xor(mi, off, 64);
          const float ol = __shfl_xor(li, off, 64);
          const float nm = fmaxf(mi, om);
          li = li * exp2f(mi - nm) + ol * exp2f(om - nm);
          mi = nm;
        }
        m[i] = mi; l[i] = li; invl[i] = 1.f / li;
      }
    }
  }
}

// ---------------------------------------------------------------------------
// K7: ao(b,s,h*64+d) = attn(bh,s,:) @ v(bh,:,d)   k-major LDS, b128 reads
// ---------------------------------------------------------------------------
__global__ __launch_bounds__(256) void k_av(
    const float* __restrict__ attn, const float* __restrict__ v,
    float* __restrict__ ao) {
  const int bh = blockIdx.y, b = bh >> 4, h = bh & 15;
  const int s0 = blockIdx.x * 64;
  const int tid = threadIdx.x, tx = tid & 15, ty = tid >> 4;
  __shared__ float As[32][68];   // As[k][s]
  __shared__ float Bs[32][68];   // Bs[k][d]
  const float* ab = attn + (size_t)bh * S_ * S_;
  const float* vb = v + (size_t)bh * S_ * HD_;
  float c[4][4] = {};
  const int srow = tid & 63, sk = (tid >> 6) * 8;     // A staging
  const int vr = tid >> 3, vd0 = (tid & 7) * 8;       // B staging
  for (int t0 = 0; t0 < S_; t0 += 32) {
    const float* app = ab + (size_t)(s0 + srow) * S_ + t0 + sk;
    float4 fa0 = *reinterpret_cast<const float4*>(app);
    float4 fa1 = *reinterpret_cast<const float4*>(app + 4);
    const float* vpp = vb + (size_t)(t0 + vr) * HD_ + vd0;
    float4 fv0 = *reinterpret_cast<const float4*>(vpp);
    float4 fv1 = *reinterpret_cast<const float4*>(vpp + 4);
    __syncthreads();
    As[sk + 0][srow] = fa0.x; As[sk + 1][srow] = fa0.y;
    As[sk + 2][srow] = fa0.z; As[sk + 3][srow] = fa0.w;
    As[sk + 4][srow] = fa1.x; As[sk + 5][srow] = fa1.y;
    As[sk + 6][srow] = fa1.z; As[sk + 7][srow] = fa1.w;
    *reinterpret_cast<float4*>(&Bs[vr][vd0]) = fv0;
    *reinterpret_cast<float4*>(&Bs[vr][vd0 + 4]) = fv1;
    __syncthreads();
#pragma unroll 8
    for (int kk = 0; kk < 32; ++kk) {
      const float4 a4 = *reinterpret_cast<const float4*>(&As[kk][ty * 4]);
      const float4 b4 = *reinterpret_cast<const float4*>(&Bs[kk][tx * 4]);
      const float a[4] = {a4.x, a4.y, a4.z, a4.w};
      const float bb[4] = {b4.x, b4.y, b4.z, b4.w};
#pragma unroll
      for (int i = 0; i < 4; ++i)
#pragma unroll
        for (int j = 0; j < 4; ++j) c[i][j] = fmaf(a[i], bb[j], c[i][j]);
    }
  }
#pragma unroll
  for (int i = 0; i < 4; ++i) {
    const int ss = s0 + ty * 4 + i;
    float* dst = ao + (size_t)(b * S_ + ss) * D_ + h * HD_;
#pragma unroll
    for (int j = 0; j < 4; ++j) dst[tx * 4 + j] = c[i][j];
  }
}

// ---------------------------------------------------------------------------
// K8: y = ao @ out_w^T + out_b  -> f32 d_out   (k-major LDS, b128 reads)
// ---------------------------------------------------------------------------
__global__ __launch_bounds__(256) void k_gemm_out(
    const float* __restrict__ a, const float* __restrict__ w,
    const float* __restrict__ bias, float* __restrict__ y) {
  __shared__ float As[32][68];
  __shared__ float Bs[32][68];
  const int tid = threadIdx.x;
  const int m0 = blockIdx.y * 64;
  const int n0 = blockIdx.x * 64;
  const int tx = tid & 15, ty = tid >> 4;
  const int srow = tid & 63, sk = (tid >> 6) * 8;
  float c[4][4] = {};
  for (int k0 = 0; k0 < D_; k0 += 32) {
    const float* apx = a + (size_t)(m0 + srow) * D_ + k0 + sk;
    const float* wpx = w + (size_t)(n0 + srow) * D_ + k0 + sk;
    float4 fa0 = *reinterpret_cast<const float4*>(apx);
    float4 fa1 = *reinterpret_cast<const float4*>(apx + 4);
    float4 fb0 = *reinterpret_cast<const float4*>(wpx);
    float4 fb1 = *reinterpret_cast<const float4*>(wpx + 4);
    __syncthreads();
    As[sk + 0][srow] = fa0.x; As[sk + 1][srow] = fa0.y;
    As[sk + 2][srow] = fa0.z; As[sk + 3][srow] = fa0.w;
    As[sk + 4][srow] = fa1.x; As[sk + 5][srow] = fa1.y;
    As[sk + 6][srow] = fa1.z; As[sk + 7][srow] = fa1.w;
    Bs[sk + 0][srow] = fb0.x; Bs[sk + 1][srow] = fb0.y;
    Bs[sk + 2][srow] = fb0.z; Bs[sk + 3][srow] = fb0.w;
    Bs[sk + 4][srow] = fb1.x; Bs[sk + 5][srow] = fb1.y;
    Bs[sk + 6][srow] = fb1.z; Bs[sk + 7][srow] = fb1.w;
    __syncthreads();
#pragma unroll 8
    for (int kk = 0; kk < 32; ++kk) {
      const float4 a4 = *reinterpret_cast<const float4*>(&As[kk][ty * 4]);
      const float4 b4 = *reinterpret_cast<const float4*>(&Bs[kk][tx * 4]);
      const float av[4] = {a4.x, a4.y, a4.z, a4.w};
      const float bv[4] = {b4.x, b4.y, b4.z, b4.w};
#pragma unroll
      for (int i = 0; i < 4; ++i)
#pragma unroll
        for (int j = 0; j < 4; ++j) c[i][j] = fmaf(av[i], bv[j], c[i][j]);
    }
  }
#pragma unroll
  for (int j = 0; j < 4; ++j) {
    const int n = n0 + tx * 4 + j;
    const float bb = bias[n];
#pragma unroll
    for (int i = 0; i < 4; ++i) {
      const int m = m0 + ty * 4 + i;
      y[(size_t)m * D_ + n] = c[i][j] + bb;
    }
  }
}

extern "C" void kernel_launch(void* const* d_in, const int* in_sizes, int n_in,
                              void* d_out, int out_size, void* d_ws, size_t ws_size,
                              hipStream_t stream) {
  const float* x = (const float*)d_in[0];
  const float* qkv_w = (const float*)d_in[1];
  const float* qkv_b = (const float*)d_in[2];
  const float* out_w = (const float*)d_in[3];
  const float* out_b = (const float*)d_in[4];

  constexpr size_t QN = (size_t)BH_ * S_ * HD_;  // 4,194,304
  float* ws = (float*)d_ws;
  float* q = ws;
  float* kbuf = q + QN;
  float* vbuf = kbuf + QN;
  float* ao = vbuf + QN;                 // (B,S,D) f32
  float* d2c = ao + QN;                  // (BH,S)
  float* sqn = d2c + BH_ * S_;
  float* mmd = sqn + BH_ * S_;
  float* d2cmax = mmd + BH_ * S_;        // (BH)
  float* mmdmax = d2cmax + BH_;
  unsigned char* lmask = (unsigned char*)(mmdmax + BH_);  // (BH,S) bytes

  float* outy = (float*)d_out;           // (B,S,D) f32
  float* attn = outy + QN;               // (BH,S,S) f32

  k_gemm_qkv<<<dim3(48, 64), dim3(256), 0, stream>>>(x, qkv_w, qkv_b, q, kbuf, vbuf);
  k_centroid<<<dim3(32), dim3(256), 0, stream>>>(x, d2c, sqn, d2cmax);
  k_kth<<<dim3(128, 32), dim3(256), 0, stream>>>(x, sqn, mmd);
  k_maxreduce<<<dim3(32), dim3(256), 0, stream>>>(mmd, mmdmax);
  k_topk<<<dim3(32), dim3(256), 0, stream>>>(d2c, mmd, d2cmax, mmdmax, lmask);
  k_attn<<<dim3(1024), dim3(256), 0, stream>>>(q, kbuf, lmask, attn);
  k_av<<<dim3(32, 32), dim3(256), 0, stream>>>(attn, vbuf, ao);
  k_gemm_out<<<dim3(16, 64), dim3(256), 0, stream>>>(ao, out_w, out_b, outy);
}